// Round 14
// baseline (184.965 us; speedup 1.0000x reference)
//
#include <hip/hip_runtime.h>

typedef __attribute__((ext_vector_type(8))) short short8;
typedef __attribute__((ext_vector_type(4))) float f32x4;
typedef __attribute__((ext_vector_type(2))) unsigned int u32x2;

constexpr int B_ = 4, T_ = 2048, D_ = 1024, H_ = 16;
constexpr int M_ = B_ * T_;          // 8192 token rows
constexpr float SCL2 = 0.1803368801111f;  // (1/sqrt(64)) * log2(e)

#if __has_builtin(__builtin_amdgcn_exp2f)
#define EXP2F __builtin_amdgcn_exp2f
#else
#define EXP2F exp2f
#endif

#define DEV __device__ __forceinline__

DEV unsigned short f2bf(float f) {   // f32 -> bf16 RNE
  unsigned int u = __builtin_bit_cast(unsigned int, f);
  u += 0x7FFFu + ((u >> 16) & 1u);
  return (unsigned short)(u >> 16);
}

DEV void gload16(const unsigned short* g, unsigned short* l) {
  __builtin_amdgcn_global_load_lds(
      (const __attribute__((address_space(1))) unsigned int*)g,
      (__attribute__((address_space(3))) unsigned int*)l, 16, 0, 0);
}

// ---------------- f32 -> bf16 conversion ----------------
__global__ __launch_bounds__(256) void cvt_bf16(const float* __restrict__ in,
                                                unsigned short* __restrict__ out,
                                                int n) {
  int i = (blockIdx.x * 256 + threadIdx.x) * 4;
  if (i >= n) return;
  float4 f = *(const float4*)(in + i);
  ushort4 o;
  o.x = f2bf(f.x); o.y = f2bf(f.y); o.z = f2bf(f.z); o.w = f2bf(f.w);
  *(ushort4*)(out + i) = o;
}

// 4 weights in one launch (1024 blocks each)
__global__ __launch_bounds__(256) void cvt_w4(const float* __restrict__ w0, const float* __restrict__ w1,
                                              const float* __restrict__ w2, const float* __restrict__ w3,
                                              unsigned short* __restrict__ o0, unsigned short* __restrict__ o1,
                                              unsigned short* __restrict__ o2, unsigned short* __restrict__ o3) {
  int sel = blockIdx.x >> 10;
  const float* in = sel == 0 ? w0 : sel == 1 ? w1 : sel == 2 ? w2 : w3;
  unsigned short* out = sel == 0 ? o0 : sel == 1 ? o1 : sel == 2 ? o2 : o3;
  int i = ((blockIdx.x & 1023) * 256 + threadIdx.x) * 4;
  float4 f = *(const float4*)(in + i);
  ushort4 o;
  o.x = f2bf(f.x); o.y = f2bf(f.y); o.z = f2bf(f.z); o.w = f2bf(f.w);
  *(ushort4*)(out + i) = o;
}

// ---------------- GEMM: C[M,N] = A[M,K] * B[N,K]^T ----------------
// 8-phase-style schedule: 512 threads (8 waves 4Mx2N, wave tile 64x64),
// BM=256 BN=128 BK=64, 2 LDS buffers (96KB -> 1 block/CU).
// Per K-tile: [issue 6 gloads(t+1)] [vmcnt(6)] [s_barrier] then 4 phases
// {ds-reads, setprio1, 8 MFMA, setprio0, s_barrier}. Counted vmcnt: tile t's
// loads were issued one full K-tile earlier; 6 newer (t+1) stay in flight.
// WAR: issue(t+1) overwrites buf of t-1, gated by prev iteration's last
// phase barrier. T2 swizzle (slot ^= row&7) on both stage-source and reads.
// OUTMODE: 1 = f32 row-major, 3 = fused QKV (tn>>3: 0-7 Q, 8-15 K, 16-23 Vt)
template <int OUTMODE>
__global__ __launch_bounds__(512, 1) void gemm_bt(const unsigned short* __restrict__ A,
                                                  const unsigned short* __restrict__ B,
                                                  void* __restrict__ C,
                                                  int M, int N, int K) {
  constexpr int BM = 256, BN = 128, BK = 64;
  __shared__ __align__(16) unsigned short a_sh[2 * BM * BK];  // 64 KB
  __shared__ __align__(16) unsigned short b_sh[2 * BN * BK];  // 32 KB

  const int tid = threadIdx.x;
  const int lane = tid & 63;
  const int w = tid >> 6;          // 0..7
  const int l15 = lane & 15, lg = lane >> 4;
  const int wr = w >> 1;           // 0..3 (M)
  const int wc = w & 1;            // 0..1 (N)

  const int nwg = gridDim.x;
  const int swz = (blockIdx.x & 7) * (nwg >> 3) + (blockIdx.x >> 3);

  const int NT = N / BN;
  const int tm = swz / NT, tn = swz % NT;
  const unsigned short* Ab = A + (size_t)tm * BM * K;
  const unsigned short* Bb = B + (size_t)tn * BN * K;

  f32x4 acc[4][4];
#pragma unroll
  for (int m = 0; m < 4; ++m)
#pragma unroll
    for (int n = 0; n < 4; ++n) acc[m][n] = (f32x4){0.f, 0.f, 0.f, 0.f};

  // issue all 6 gloads (4 A-rounds + 2 B-rounds) of one K-tile, src-swizzled
  auto issue = [&](int buf, int kt) {
    int k0 = kt * BK;
#pragma unroll
    for (int r = 0; r < 4; ++r) {
      int c = r * 512 + tid;
      int row = c >> 3, s = c & 7;
      gload16(Ab + (size_t)row * K + k0 + 8 * (s ^ (row & 7)),
              a_sh + buf * BM * BK + (r * 512 + w * 64) * 8);
    }
#pragma unroll
    for (int r = 0; r < 2; ++r) {
      int c = r * 512 + tid;
      int row = c >> 3, s = c & 7;
      gload16(Bb + (size_t)row * K + k0 + 8 * (s ^ (row & 7)),
              b_sh + buf * BN * BK + (r * 512 + w * 64) * 8);
    }
  };

  const int NK = K / BK;           // 16
  issue(0, 0);
  issue(1, 1);

  for (int kt = 0; kt < NK; ++kt) {
    if (kt >= 1 && kt + 1 < NK) issue((kt + 1) & 1, kt + 1);
    __builtin_amdgcn_sched_barrier(0);
    if (kt + 1 < NK) asm volatile("s_waitcnt vmcnt(6)" ::: "memory");
    else             asm volatile("s_waitcnt vmcnt(0)" ::: "memory");
    __builtin_amdgcn_sched_barrier(0);
    __builtin_amdgcn_s_barrier();      // collectivize vmcnt: all waves' tile-kt landed
    __builtin_amdgcn_sched_barrier(0);

    const int cur = kt & 1;
    const unsigned short* ab = a_sh + cur * BM * BK;
    const unsigned short* bb = b_sh + cur * BN * BK;
    short8 af[4][2], bf[4][2];
    auto rdA = [&](int m, int kk) {
      int row = wr * 64 + m * 16 + l15;
      int slot = (kk * 4 + lg) ^ (row & 7);
      return *(const short8*)(ab + row * 64 + slot * 8);
    };
    auto rdB = [&](int n, int kk) {
      int row = wc * 64 + n * 16 + l15;
      int slot = (kk * 4 + lg) ^ (row & 7);
      return *(const short8*)(bb + row * 64 + slot * 8);
    };
#define MM(m, n, kk) acc[m][n] = __builtin_amdgcn_mfma_f32_16x16x32_bf16(af[m][kk], bf[n][kk], acc[m][n], 0, 0, 0)

    // phase 0: m{0,1} x n{0,1}
    af[0][0] = rdA(0, 0); af[0][1] = rdA(0, 1);
    af[1][0] = rdA(1, 0); af[1][1] = rdA(1, 1);
    bf[0][0] = rdB(0, 0); bf[0][1] = rdB(0, 1);
    bf[1][0] = rdB(1, 0); bf[1][1] = rdB(1, 1);
    __builtin_amdgcn_s_setprio(1);
    MM(0, 0, 0); MM(0, 0, 1); MM(0, 1, 0); MM(0, 1, 1);
    MM(1, 0, 0); MM(1, 0, 1); MM(1, 1, 0); MM(1, 1, 1);
    __builtin_amdgcn_s_setprio(0);
    __builtin_amdgcn_s_barrier();
    __builtin_amdgcn_sched_barrier(0);

    // phase 1: m{2,3} x n{0,1}
    af[2][0] = rdA(2, 0); af[2][1] = rdA(2, 1);
    af[3][0] = rdA(3, 0); af[3][1] = rdA(3, 1);
    __builtin_amdgcn_s_setprio(1);
    MM(2, 0, 0); MM(2, 0, 1); MM(2, 1, 0); MM(2, 1, 1);
    MM(3, 0, 0); MM(3, 0, 1); MM(3, 1, 0); MM(3, 1, 1);
    __builtin_amdgcn_s_setprio(0);
    __builtin_amdgcn_s_barrier();
    __builtin_amdgcn_sched_barrier(0);

    // phase 2: m{2,3} x n{2,3}
    bf[2][0] = rdB(2, 0); bf[2][1] = rdB(2, 1);
    bf[3][0] = rdB(3, 0); bf[3][1] = rdB(3, 1);
    __builtin_amdgcn_s_setprio(1);
    MM(2, 2, 0); MM(2, 2, 1); MM(2, 3, 0); MM(2, 3, 1);
    MM(3, 2, 0); MM(3, 2, 1); MM(3, 3, 0); MM(3, 3, 1);
    __builtin_amdgcn_s_setprio(0);
    __builtin_amdgcn_s_barrier();
    __builtin_amdgcn_sched_barrier(0);

    // phase 3: m{0,1} x n{2,3} (no new reads)
    __builtin_amdgcn_s_setprio(1);
    MM(0, 2, 0); MM(0, 2, 1); MM(0, 3, 0); MM(0, 3, 1);
    MM(1, 2, 0); MM(1, 2, 1); MM(1, 3, 0); MM(1, 3, 1);
    __builtin_amdgcn_s_setprio(0);
    __builtin_amdgcn_s_barrier();      // WAR gate for next issue
    __builtin_amdgcn_sched_barrier(0);
#undef MM
  }

  const int row0 = tm * BM + wr * 64 + lg * 4;
  const int col0 = tn * BN + wc * 64 + l15;
#pragma unroll
  for (int m = 0; m < 4; ++m)
#pragma unroll
    for (int n = 0; n < 4; ++n) {
      if (OUTMODE == 3) {
        const int region = tn >> 3;               // 0=Q, 1=K, 2=V
        const int nc = col0 - (region << 10) + n * 16;
        const int mm = row0 + m * 16;
        if (region == 2) {
          // Vt-per-head: [(b*16+h)][d][s], r consecutive in s
          size_t base = (size_t)2 * 8388608 +
                        ((size_t)((mm >> 11) * 16 + (nc >> 6))) * 131072 +
                        (size_t)(nc & 63) * 2048 + (mm & 2047);
          ushort4 pk;
          pk.x = f2bf(acc[m][n][0]); pk.y = f2bf(acc[m][n][1]);
          pk.z = f2bf(acc[m][n][2]); pk.w = f2bf(acc[m][n][3]);
          *(ushort4*)((unsigned short*)C + base) = pk;
        } else {
          unsigned short* dst = (unsigned short*)C + (size_t)region * 8388608;
#pragma unroll
          for (int r = 0; r < 4; ++r)
            dst[(size_t)(mm + r) * 1024 + nc] = f2bf(acc[m][n][r]);
        }
      } else {
#pragma unroll
        for (int r = 0; r < 4; ++r) {
          size_t idx = (size_t)(row0 + m * 16 + r) * N + (col0 + n * 16);
          if (OUTMODE == 1)
            ((float*)C)[idx] = acc[m][n][r];
          else
            ((unsigned short*)C)[idx] = f2bf(acc[m][n][r]);
        }
      }
    }
}

// ---------------- causal flash attention (swapped-QK, KB=64, QB=128) --------
// Unchanged from round 13.
__global__ __launch_bounds__(256, 3) void attn(const unsigned short* __restrict__ Q,
                                               const unsigned short* __restrict__ K,
                                               const unsigned short* __restrict__ Vt,
                                               unsigned short* __restrict__ Y) {
  __shared__ __align__(16) unsigned short k_sh[2][64 * 64];
  __shared__ __align__(16) unsigned short v_sh[2][64 * 64];   // [d][s], swizzled
  __shared__ __align__(16) unsigned short p_sh[4][32][72];    // per-wave P

  const int tid = threadIdx.x;
  const int lane = tid & 63;
  const int w = tid >> 6;
  const int l15 = lane & 15, lg = lane >> 4;

  const int bid = blockIdx.x;
  const int qt_blk = 15 - (bid >> 6);          // all heavy blocks dispatch first
  const int bh = bid & 63;
  const int h = bh & 15;
  const int b = bh >> 4;
  const int q0 = qt_blk * 128;
  const int qq0 = q0 + 32 * w;                 // this wave's first q-row

  const unsigned short* Qp = Q + ((size_t)(b * T_ + q0)) * D_ + h * 64;
  const unsigned short* Kp = K + ((size_t)(b * T_)) * D_ + h * 64;
  const unsigned short* Vtp = Vt + (size_t)bh * 131072;   // [64 d][2048 s]

  auto stK = [&](int buf, int kv0) {
#pragma unroll
    for (int j = 0; j < 2; ++j) {
      int c = j * 256 + tid;
      int row = c >> 3;
      gload16(Kp + (size_t)(kv0 + row) * D_ + 8 * ((c & 7) ^ (row & 7)),
              &k_sh[buf][(j * 256 + w * 64) * 8]);
    }
  };
  auto stV = [&](int buf, int kv0) {
#pragma unroll
    for (int j = 0; j < 2; ++j) {
      int c = j * 256 + tid;
      int d = c >> 3;
      gload16(Vtp + (size_t)d * 2048 + kv0 + 8 * ((c & 7) ^ (d & 7)),
              &v_sh[buf][(j * 256 + w * 64) * 8]);
    }
  };

  // Q fragments direct global -> registers (B-frag: row = q, k-contig)
  short8 qf[2][2];
#pragma unroll
  for (int qt = 0; qt < 2; ++qt)
#pragma unroll
    for (int kk = 0; kk < 2; ++kk)
      qf[qt][kk] = *(const short8*)(Qp + (size_t)(32 * w + 16 * qt + l15) * D_ + 32 * kk + 8 * lg);

  stK(0, 0);
  stV(0, 0);
  __syncthreads();

  unsigned short* p_w = &p_sh[w][0][0];

  const float NEGINF = -__builtin_inff();
  float ml[2] = {NEGINF, NEGINF};
  float ll[2] = {0.f, 0.f};
  f32x4 o[2][4];
#pragma unroll
  for (int qt = 0; qt < 2; ++qt)
#pragma unroll
    for (int t = 0; t < 4; ++t) o[qt][t] = (f32x4){0.f, 0.f, 0.f, 0.f};

  const int NI = 2 * qt_blk + 2;
  int cur = 0;
  for (int i = 0; i < NI; ++i) {
    const int kv0 = i * 64;
    if (i + 1 < NI) { stK(cur ^ 1, kv0 + 64); stV(cur ^ 1, kv0 + 64); }

    const bool active = (kv0 <= qq0 + 31);
    if (active) {
      // ---- S^T = K * Q^T  (16 MFMA) ----
      f32x4 sacc[2][4];
#pragma unroll
      for (int qt = 0; qt < 2; ++qt)
#pragma unroll
        for (int t = 0; t < 4; ++t) sacc[qt][t] = (f32x4){0.f, 0.f, 0.f, 0.f};
      const char* kb = (const char*)k_sh[cur];
      __builtin_amdgcn_s_setprio(1);
#pragma unroll
      for (int t = 0; t < 4; ++t) {
        int sr = 16 * t + l15;
        int sw = (sr & 7) << 4;
        short8 kf0 = *(const short8*)(kb + sr * 128 + ((16 * lg) ^ sw));
        short8 kf1 = *(const short8*)(kb + sr * 128 + ((64 + 16 * lg) ^ sw));
#pragma unroll
        for (int qt = 0; qt < 2; ++qt) {
          sacc[qt][t] = __builtin_amdgcn_mfma_f32_16x16x32_bf16(kf0, qf[qt][0], sacc[qt][t], 0, 0, 0);
          sacc[qt][t] = __builtin_amdgcn_mfma_f32_16x16x32_bf16(kf1, qf[qt][1], sacc[qt][t], 0, 0, 0);
        }
      }
      __builtin_amdgcn_s_setprio(0);

      // ---- online softmax per q-tile (in-register, T13 defer-max) ----
      float corr[2];
      bool defer[2];
#pragma unroll
      for (int qt = 0; qt < 2; ++qt) {
        const bool nomask = (kv0 + 63) <= (qq0 + 16 * qt);   // wave-uniform
        float sv[16];
        if (nomask) {
#pragma unroll
          for (int t = 0; t < 4; ++t)
#pragma unroll
            for (int r = 0; r < 4; ++r) sv[4 * t + r] = sacc[qt][t][r];
        } else {
          const int qg = qq0 + 16 * qt + l15;
#pragma unroll
          for (int t = 0; t < 4; ++t)
#pragma unroll
            for (int r = 0; r < 4; ++r) {
              int sg = kv0 + 16 * t + 4 * lg + r;
              sv[4 * t + r] = (sg <= qg) ? sacc[qt][t][r] : NEGINF;
            }
        }
        float a8[8], a4[4], a2[2];
#pragma unroll
        for (int k = 0; k < 8; ++k) a8[k] = fmaxf(sv[k], sv[k + 8]);
#pragma unroll
        for (int k = 0; k < 4; ++k) a4[k] = fmaxf(a8[k], a8[k + 4]);
        a2[0] = fmaxf(a4[0], a4[2]); a2[1] = fmaxf(a4[1], a4[3]);
        float mx = fmaxf(a2[0], a2[1]);
        mx = fmaxf(mx, __shfl_xor(mx, 16));
        mx = fmaxf(mx, __shfl_xor(mx, 32));
        // T13: keep old max when growth small (P bounded by 2^(8*SCL2) ~ 2.7)
        defer[qt] = (__all(mx <= ml[qt] + 8.0f) != 0);
        float mnew = defer[qt] ? ml[qt] : fmaxf(ml[qt], mx);
        corr[qt] = defer[qt] ? 1.0f : EXP2F((ml[qt] - mnew) * SCL2);
        float nms2 = mnew * SCL2;
        float pv[16];
#pragma unroll
        for (int k = 0; k < 16; ++k) pv[k] = EXP2F(fmaf(sv[k], SCL2, -nms2));
        float s8[8], s4[4], s2[2];
#pragma unroll
        for (int k = 0; k < 8; ++k) s8[k] = pv[k] + pv[k + 8];
#pragma unroll
        for (int k = 0; k < 4; ++k) s4[k] = s8[k] + s8[k + 4];
        s2[0] = s4[0] + s4[2]; s2[1] = s4[1] + s4[3];
        float ps = s2[0] + s2[1];
        ps += __shfl_xor(ps, 16);
        ps += __shfl_xor(ps, 32);
        ll[qt] = ll[qt] * corr[qt] + ps;
        ml[qt] = mnew;
        // pack P -> LDS via v_cvt_pk_bf16_f32 (RNE, lo=src0)
#pragma unroll
        for (int t = 0; t < 4; ++t) {
          unsigned lo, hi;
          asm("v_cvt_pk_bf16_f32 %0, %1, %2" : "=v"(lo) : "v"(pv[4 * t]), "v"(pv[4 * t + 1]));
          asm("v_cvt_pk_bf16_f32 %0, %1, %2" : "=v"(hi) : "v"(pv[4 * t + 2]), "v"(pv[4 * t + 3]));
          u32x2 pk = {lo, hi};
          *(u32x2*)(void*)(p_w + (16 * qt + l15) * 72 + 16 * t + 4 * lg) = pk;
        }
      }
      asm volatile("" ::: "memory");  // order P stores before P frag loads

      // ---- rescale O (skipped when deferred) ----
#pragma unroll
      for (int qt = 0; qt < 2; ++qt)
        if (!defer[qt]) {
#pragma unroll
          for (int r = 0; r < 4; ++r) {
            float cr = __shfl(corr[qt], 4 * lg + r);
#pragma unroll
            for (int t = 0; t < 4; ++t) o[qt][t][r] *= cr;
          }
        }

      // ---- O += P * V  (16 MFMA) ----
      short8 pa[2][2];
#pragma unroll
      for (int qt = 0; qt < 2; ++qt)
#pragma unroll
        for (int kk = 0; kk < 2; ++kk)
          pa[qt][kk] = *(const short8*)(p_w + (16 * qt + l15) * 72 + kk * 32 + 8 * lg);

      const char* vbT = (const char*)v_sh[cur];
      __builtin_amdgcn_s_setprio(1);
#pragma unroll
      for (int t = 0; t < 4; ++t) {
        int dr = 16 * t + l15;
        int sw = (dr & 7) << 4;
        short8 vf0 = *(const short8*)(vbT + dr * 128 + ((16 * lg) ^ sw));
        short8 vf1 = *(const short8*)(vbT + dr * 128 + ((64 + 16 * lg) ^ sw));
#pragma unroll
        for (int qt = 0; qt < 2; ++qt) {
          o[qt][t] = __builtin_amdgcn_mfma_f32_16x16x32_bf16(pa[qt][0], vf0, o[qt][t], 0, 0, 0);
          o[qt][t] = __builtin_amdgcn_mfma_f32_16x16x32_bf16(pa[qt][1], vf1, o[qt][t], 0, 0, 0);
        }
      }
      __builtin_amdgcn_s_setprio(0);
    }
    __syncthreads();
    cur ^= 1;
  }

  // ---- epilogue: Y[b, q, h*64 + d] = O / l ----
#pragma unroll
  for (int qt = 0; qt < 2; ++qt) {
    float linv = 1.0f / ll[qt];
#pragma unroll
    for (int r = 0; r < 4; ++r) {
      float li = __shfl(linv, 4 * lg + r);
      int qg = qq0 + 16 * qt + 4 * lg + r;
      unsigned short* Yp = Y + ((size_t)(b * T_ + qg)) * D_ + h * 64;
#pragma unroll
      for (int t = 0; t < 4; ++t)
        Yp[16 * t + l15] = f2bf(o[qt][t][r] * li);
    }
  }
}

// ---------------- launch ----------------
extern "C" void kernel_launch(void* const* d_in, const int* in_sizes, int n_in,
                              void* d_out, int out_size, void* d_ws, size_t ws_size,
                              hipStream_t stream) {
  const float* x  = (const float*)d_in[0];
  const float* Wq = (const float*)d_in[1];
  const float* Wk = (const float*)d_in[2];
  const float* Wv = (const float*)d_in[3];
  const float* Wo = (const float*)d_in[4];
  float* out = (float*)d_out;

  const size_t NX = (size_t)M_ * D_;
  const size_t NW = (size_t)D_ * D_;
  const size_t need = (4 * NX + 4 * NW) * sizeof(unsigned short);
  if (ws_size < need) return;

  unsigned short* ws  = (unsigned short*)d_ws;
  unsigned short* xb  = ws;
  unsigned short* wqb = xb + NX;   // wqb/wkb/wvb contiguous = stacked QKV weight
  unsigned short* wkb = wqb + NW;
  unsigned short* wvb = wkb + NW;
  unsigned short* wob = wvb + NW;
  unsigned short* Qb  = wob + NW;  // Qb/Kb/Vtb contiguous = fused-QKV output
  unsigned short* Yb  = xb;        // alias: x dead after QKV projections

  cvt_bf16<<<(int)(NX / 1024), 256, 0, stream>>>(x, xb, (int)NX);
  cvt_w4<<<4096, 256, 0, stream>>>(Wq, Wk, Wv, Wo, wqb, wkb, wvb, wob);

  // fused QKV projection: C[8192, 3072] = x @ [Wq;Wk;Wv]^T
  // grid 32x24 = 768 = exactly 3 rounds at 1 block/CU
  gemm_bt<3><<<(M_ / 256) * (3072 / 128), 512, 0, stream>>>(xb, wqb, Qb, M_, 3072, D_);

  attn<<<B_ * H_ * (T_ / 128), 256, 0, stream>>>(Qb, Qb + NX, Qb + 2 * NX, Yb);

  // Wo: grid 32x8 = 256 = exactly 1 round
  gemm_bt<1><<<(M_ / 256) * (D_ / 128), 512, 0, stream>>>(Yb, wob, out, M_, D_, D_);
}

// Round 15
// 164.819 us; speedup vs baseline: 1.1222x; 1.1222x over previous
//
#include <hip/hip_runtime.h>

typedef __attribute__((ext_vector_type(8))) short short8;
typedef __attribute__((ext_vector_type(4))) float f32x4;
typedef __attribute__((ext_vector_type(2))) unsigned int u32x2;

constexpr int B_ = 4, T_ = 2048, D_ = 1024, H_ = 16;
constexpr int M_ = B_ * T_;          // 8192 token rows
constexpr float SCL2 = 0.1803368801111f;  // (1/sqrt(64)) * log2(e)

#if __has_builtin(__builtin_amdgcn_exp2f)
#define EXP2F __builtin_amdgcn_exp2f
#else
#define EXP2F exp2f
#endif

#define DEV __device__ __forceinline__

DEV unsigned short f2bf(float f) {   // f32 -> bf16 RNE
  unsigned int u = __builtin_bit_cast(unsigned int, f);
  u += 0x7FFFu + ((u >> 16) & 1u);
  return (unsigned short)(u >> 16);
}

DEV void gload16(const unsigned short* g, unsigned short* l) {
  __builtin_amdgcn_global_load_lds(
      (const __attribute__((address_space(1))) unsigned int*)g,
      (__attribute__((address_space(3))) unsigned int*)l, 16, 0, 0);
}

// ---------------- f32 -> bf16 conversion (x + 4 weights, one launch) -------
__global__ __launch_bounds__(256) void cvt_all(const float* __restrict__ x,
                                               const float* __restrict__ w0, const float* __restrict__ w1,
                                               const float* __restrict__ w2, const float* __restrict__ w3,
                                               unsigned short* __restrict__ xb,
                                               unsigned short* __restrict__ o0, unsigned short* __restrict__ o1,
                                               unsigned short* __restrict__ o2, unsigned short* __restrict__ o3) {
  int b = blockIdx.x;
  const float* in;
  unsigned short* out;
  int blk;
  if (b < 8192) { in = x; out = xb; blk = b; }
  else {
    int s = (b - 8192) >> 10;
    blk = (b - 8192) & 1023;
    in  = s == 0 ? w0 : s == 1 ? w1 : s == 2 ? w2 : w3;
    out = s == 0 ? o0 : s == 1 ? o1 : s == 2 ? o2 : o3;
  }
  int i = (blk * 256 + threadIdx.x) * 4;
  float4 f = *(const float4*)(in + i);
  ushort4 o;
  o.x = f2bf(f.x); o.y = f2bf(f.y); o.z = f2bf(f.z); o.w = f2bf(f.w);
  *(ushort4*)(out + i) = o;
}

// ---------------- GEMM: C[M,N] = A[M,K] * B[N,K]^T (round-13 structure) ----
// OUTMODE: 0 = bf16 row-major, 1 = f32 row-major,
//          3 = fused QKV: region by tn (0-7 Q, 8-15 K, 16-23 Vt-per-head)
// BK=64: 32 MFMA per barrier pair. T2 XOR-swizzle (slot ^= row&7): staged via
// pre-swizzled GLOBAL source (gload_lds dest stays linear), reads with
// matching XOR -> 0 bank conflicts (verified r13).
template <int OUTMODE>
__global__ __launch_bounds__(256, 2) void gemm_bt(const unsigned short* __restrict__ A,
                                                  const unsigned short* __restrict__ B,
                                                  void* __restrict__ C,
                                                  int M, int N, int K) {
  constexpr int BM = 128, BN = 128, BK = 64;
  __shared__ __align__(16) unsigned short a_sh[2 * BM * BK];  // 32 KB
  __shared__ __align__(16) unsigned short b_sh[2 * BN * BK];  // 32 KB

  const int tid = threadIdx.x;
  const int lane = tid & 63;
  const int w = tid >> 6;
  const int l15 = lane & 15, lg = lane >> 4;
  const int wr = w >> 1, wc = w & 1;

  // XCD-chunked bijective swizzle: each XCD gets a contiguous run of tiles
  const int nwg = gridDim.x;
  const int swz = (blockIdx.x & 7) * (nwg >> 3) + (blockIdx.x >> 3);

  const int NT = N / BN;
  const int tm = swz / NT, tn = swz % NT;
  const unsigned short* Ab = A + (size_t)tm * BM * K;
  const unsigned short* Bb = B + (size_t)tn * BN * K;

  f32x4 acc[4][4];
#pragma unroll
  for (int m = 0; m < 4; ++m)
#pragma unroll
    for (int n = 0; n < 4; ++n) acc[m][n] = (f32x4){0.f, 0.f, 0.f, 0.f};

  // stage one BK=64 tile of A and B, source-swizzled: slot s of row r holds
  // global k8-group (s ^ (r&7)).
  auto stage = [&](int buf, int kt) {
    int k0 = kt * BK;
#pragma unroll
    for (int rnd = 0; rnd < 4; ++rnd) {
      int c = rnd * 256 + tid;            // 16B chunk id, 0..1023
      int row = c >> 3, s = c & 7;        // 8 chunks per 64-elem row
      int koff = k0 + 8 * (s ^ (row & 7));
      unsigned short* ldst_a = a_sh + buf * BM * BK + (rnd * 256 + w * 64) * 8;
      unsigned short* ldst_b = b_sh + buf * BN * BK + (rnd * 256 + w * 64) * 8;
      gload16(Ab + (size_t)row * K + koff, ldst_a);
      gload16(Bb + (size_t)row * K + koff, ldst_b);
    }
  };

  stage(0, 0);
  int cur = 0;
  const int NK = K / BK;                  // 16
  for (int kt = 0; kt < NK; ++kt) {
    __syncthreads();                      // drains vmcnt -> buf[cur] ready
    if (kt + 1 < NK) stage(cur ^ 1, kt + 1);
    const unsigned short* ab = a_sh + cur * BM * BK;
    const unsigned short* bb = b_sh + cur * BN * BK;
#pragma unroll
    for (int kk = 0; kk < 2; ++kk) {
      short8 af[4], bf8[4];
#pragma unroll
      for (int m = 0; m < 4; ++m) {
        int row = wr * 64 + m * 16 + l15;
        int slot = (kk * 4 + lg) ^ (row & 7);
        af[m] = *(const short8*)(ab + row * 64 + slot * 8);
      }
#pragma unroll
      for (int n = 0; n < 4; ++n) {
        int row = wc * 64 + n * 16 + l15;
        int slot = (kk * 4 + lg) ^ (row & 7);
        bf8[n] = *(const short8*)(bb + row * 64 + slot * 8);
      }
#pragma unroll
      for (int m = 0; m < 4; ++m)
#pragma unroll
        for (int n = 0; n < 4; ++n)
          acc[m][n] = __builtin_amdgcn_mfma_f32_16x16x32_bf16(af[m], bf8[n], acc[m][n], 0, 0, 0);
    }
    cur ^= 1;
  }

  const int row0 = tm * BM + wr * 64 + lg * 4;
  const int col0 = tn * BN + wc * 64 + l15;
#pragma unroll
  for (int m = 0; m < 4; ++m)
#pragma unroll
    for (int n = 0; n < 4; ++n) {
      if (OUTMODE == 3) {
        const int region = tn >> 3;               // 0=Q, 1=K, 2=V
        const int nc = col0 - (region << 10) + n * 16;
        const int mm = row0 + m * 16;
        if (region == 2) {
          // Vt-per-head: [(b*16+h)][d][s], r consecutive in s
          size_t base = (size_t)2 * 8388608 +
                        ((size_t)((mm >> 11) * 16 + (nc >> 6))) * 131072 +
                        (size_t)(nc & 63) * 2048 + (mm & 2047);
          ushort4 pk;
          pk.x = f2bf(acc[m][n][0]); pk.y = f2bf(acc[m][n][1]);
          pk.z = f2bf(acc[m][n][2]); pk.w = f2bf(acc[m][n][3]);
          *(ushort4*)((unsigned short*)C + base) = pk;
        } else {
          unsigned short* dst = (unsigned short*)C + (size_t)region * 8388608;
#pragma unroll
          for (int r = 0; r < 4; ++r)
            dst[(size_t)(mm + r) * 1024 + nc] = f2bf(acc[m][n][r]);
        }
      } else {
#pragma unroll
        for (int r = 0; r < 4; ++r) {
          size_t idx = (size_t)(row0 + m * 16 + r) * N + (col0 + n * 16);
          if (OUTMODE == 1)
            ((float*)C)[idx] = acc[m][n][r];
          else
            ((unsigned short*)C)[idx] = f2bf(acc[m][n][r]);
        }
      }
    }
}

// ---------------- causal flash attention (swapped-QK, KB=64, QB=128) --------
// Round-13 structure + bh-locality XCD swizzle: bid -> (qt heavy-first,
// bh = (bid&7)*8 + ((bid>>3)&7)) so each XCD's round-robin slot reuses only
// 8 (b,h) pairs -> per-XCD KV footprint 4 MB (= L2). Bijective.
__global__ __launch_bounds__(256, 3) void attn(const unsigned short* __restrict__ Q,
                                               const unsigned short* __restrict__ K,
                                               const unsigned short* __restrict__ Vt,
                                               unsigned short* __restrict__ Y) {
  __shared__ __align__(16) unsigned short k_sh[2][64 * 64];
  __shared__ __align__(16) unsigned short v_sh[2][64 * 64];   // [d][s], swizzled
  __shared__ __align__(16) unsigned short p_sh[4][32][72];    // per-wave P

  const int tid = threadIdx.x;
  const int lane = tid & 63;
  const int w = tid >> 6;
  const int l15 = lane & 15, lg = lane >> 4;

  const int bid = blockIdx.x;
  const int qt_blk = 15 - (bid >> 6);          // all heavy blocks dispatch first
  const int bh = (bid & 7) * 8 + ((bid >> 3) & 7);  // XCD-local KV reuse
  const int h = bh & 15;
  const int b = bh >> 4;
  const int q0 = qt_blk * 128;
  const int qq0 = q0 + 32 * w;                 // this wave's first q-row

  const unsigned short* Qp = Q + ((size_t)(b * T_ + q0)) * D_ + h * 64;
  const unsigned short* Kp = K + ((size_t)(b * T_)) * D_ + h * 64;
  const unsigned short* Vtp = Vt + (size_t)bh * 131072;   // [64 d][2048 s]

  auto stK = [&](int buf, int kv0) {
#pragma unroll
    for (int j = 0; j < 2; ++j) {
      int c = j * 256 + tid;
      int row = c >> 3;
      gload16(Kp + (size_t)(kv0 + row) * D_ + 8 * ((c & 7) ^ (row & 7)),
              &k_sh[buf][(j * 256 + w * 64) * 8]);
    }
  };
  auto stV = [&](int buf, int kv0) {
#pragma unroll
    for (int j = 0; j < 2; ++j) {
      int c = j * 256 + tid;
      int d = c >> 3;
      gload16(Vtp + (size_t)d * 2048 + kv0 + 8 * ((c & 7) ^ (d & 7)),
              &v_sh[buf][(j * 256 + w * 64) * 8]);
    }
  };

  // Q fragments direct global -> registers (B-frag: row = q, k-contig)
  short8 qf[2][2];
#pragma unroll
  for (int qt = 0; qt < 2; ++qt)
#pragma unroll
    for (int kk = 0; kk < 2; ++kk)
      qf[qt][kk] = *(const short8*)(Qp + (size_t)(32 * w + 16 * qt + l15) * D_ + 32 * kk + 8 * lg);

  stK(0, 0);
  stV(0, 0);
  __syncthreads();

  unsigned short* p_w = &p_sh[w][0][0];

  const float NEGINF = -__builtin_inff();
  float ml[2] = {NEGINF, NEGINF};
  float ll[2] = {0.f, 0.f};
  f32x4 o[2][4];
#pragma unroll
  for (int qt = 0; qt < 2; ++qt)
#pragma unroll
    for (int t = 0; t < 4; ++t) o[qt][t] = (f32x4){0.f, 0.f, 0.f, 0.f};

  const int NI = 2 * qt_blk + 2;
  int cur = 0;
  for (int i = 0; i < NI; ++i) {
    const int kv0 = i * 64;
    if (i + 1 < NI) { stK(cur ^ 1, kv0 + 64); stV(cur ^ 1, kv0 + 64); }

    const bool active = (kv0 <= qq0 + 31);
    if (active) {
      // ---- S^T = K * Q^T  (16 MFMA) ----
      f32x4 sacc[2][4];
#pragma unroll
      for (int qt = 0; qt < 2; ++qt)
#pragma unroll
        for (int t = 0; t < 4; ++t) sacc[qt][t] = (f32x4){0.f, 0.f, 0.f, 0.f};
      const char* kb = (const char*)k_sh[cur];
      __builtin_amdgcn_s_setprio(1);
#pragma unroll
      for (int t = 0; t < 4; ++t) {
        int sr = 16 * t + l15;
        int sw = (sr & 7) << 4;
        short8 kf0 = *(const short8*)(kb + sr * 128 + ((16 * lg) ^ sw));
        short8 kf1 = *(const short8*)(kb + sr * 128 + ((64 + 16 * lg) ^ sw));
#pragma unroll
        for (int qt = 0; qt < 2; ++qt) {
          sacc[qt][t] = __builtin_amdgcn_mfma_f32_16x16x32_bf16(kf0, qf[qt][0], sacc[qt][t], 0, 0, 0);
          sacc[qt][t] = __builtin_amdgcn_mfma_f32_16x16x32_bf16(kf1, qf[qt][1], sacc[qt][t], 0, 0, 0);
        }
      }
      __builtin_amdgcn_s_setprio(0);

      // ---- online softmax per q-tile (in-register, T13 defer-max) ----
      float corr[2];
      bool defer[2];
#pragma unroll
      for (int qt = 0; qt < 2; ++qt) {
        const bool nomask = (kv0 + 63) <= (qq0 + 16 * qt);   // wave-uniform
        float sv[16];
        if (nomask) {
#pragma unroll
          for (int t = 0; t < 4; ++t)
#pragma unroll
            for (int r = 0; r < 4; ++r) sv[4 * t + r] = sacc[qt][t][r];
        } else {
          const int qg = qq0 + 16 * qt + l15;
#pragma unroll
          for (int t = 0; t < 4; ++t)
#pragma unroll
            for (int r = 0; r < 4; ++r) {
              int sg = kv0 + 16 * t + 4 * lg + r;
              sv[4 * t + r] = (sg <= qg) ? sacc[qt][t][r] : NEGINF;
            }
        }
        float a8[8], a4[4], a2[2];
#pragma unroll
        for (int k = 0; k < 8; ++k) a8[k] = fmaxf(sv[k], sv[k + 8]);
#pragma unroll
        for (int k = 0; k < 4; ++k) a4[k] = fmaxf(a8[k], a8[k + 4]);
        a2[0] = fmaxf(a4[0], a4[2]); a2[1] = fmaxf(a4[1], a4[3]);
        float mx = fmaxf(a2[0], a2[1]);
        mx = fmaxf(mx, __shfl_xor(mx, 16));
        mx = fmaxf(mx, __shfl_xor(mx, 32));
        // T13: keep old max when growth small (P bounded by 2^(8*SCL2) ~ 2.7)
        defer[qt] = (__all(mx <= ml[qt] + 8.0f) != 0);
        float mnew = defer[qt] ? ml[qt] : fmaxf(ml[qt], mx);
        corr[qt] = defer[qt] ? 1.0f : EXP2F((ml[qt] - mnew) * SCL2);
        float nms2 = mnew * SCL2;
        float pv[16];
#pragma unroll
        for (int k = 0; k < 16; ++k) pv[k] = EXP2F(fmaf(sv[k], SCL2, -nms2));
        float s8[8], s4[4], s2[2];
#pragma unroll
        for (int k = 0; k < 8; ++k) s8[k] = pv[k] + pv[k + 8];
#pragma unroll
        for (int k = 0; k < 4; ++k) s4[k] = s8[k] + s8[k + 4];
        s2[0] = s4[0] + s4[2]; s2[1] = s4[1] + s4[3];
        float ps = s2[0] + s2[1];
        ps += __shfl_xor(ps, 16);
        ps += __shfl_xor(ps, 32);
        ll[qt] = ll[qt] * corr[qt] + ps;
        ml[qt] = mnew;
        // pack P -> LDS via v_cvt_pk_bf16_f32 (RNE, lo=src0)
#pragma unroll
        for (int t = 0; t < 4; ++t) {
          unsigned lo, hi;
          asm("v_cvt_pk_bf16_f32 %0, %1, %2" : "=v"(lo) : "v"(pv[4 * t]), "v"(pv[4 * t + 1]));
          asm("v_cvt_pk_bf16_f32 %0, %1, %2" : "=v"(hi) : "v"(pv[4 * t + 2]), "v"(pv[4 * t + 3]));
          u32x2 pk = {lo, hi};
          *(u32x2*)(void*)(p_w + (16 * qt + l15) * 72 + 16 * t + 4 * lg) = pk;
        }
      }
      asm volatile("" ::: "memory");  // order P stores before P frag loads

      // ---- rescale O (skipped when deferred) ----
#pragma unroll
      for (int qt = 0; qt < 2; ++qt)
        if (!defer[qt]) {
#pragma unroll
          for (int r = 0; r < 4; ++r) {
            float cr = __shfl(corr[qt], 4 * lg + r);
#pragma unroll
            for (int t = 0; t < 4; ++t) o[qt][t][r] *= cr;
          }
        }

      // ---- O += P * V  (16 MFMA) ----
      short8 pa[2][2];
#pragma unroll
      for (int qt = 0; qt < 2; ++qt)
#pragma unroll
        for (int kk = 0; kk < 2; ++kk)
          pa[qt][kk] = *(const short8*)(p_w + (16 * qt + l15) * 72 + kk * 32 + 8 * lg);

      const char* vbT = (const char*)v_sh[cur];
      __builtin_amdgcn_s_setprio(1);
#pragma unroll
      for (int t = 0; t < 4; ++t) {
        int dr = 16 * t + l15;
        int sw = (dr & 7) << 4;
        short8 vf0 = *(const short8*)(vbT + dr * 128 + ((16 * lg) ^ sw));
        short8 vf1 = *(const short8*)(vbT + dr * 128 + ((64 + 16 * lg) ^ sw));
#pragma unroll
        for (int qt = 0; qt < 2; ++qt) {
          o[qt][t] = __builtin_amdgcn_mfma_f32_16x16x32_bf16(pa[qt][0], vf0, o[qt][t], 0, 0, 0);
          o[qt][t] = __builtin_amdgcn_mfma_f32_16x16x32_bf16(pa[qt][1], vf1, o[qt][t], 0, 0, 0);
        }
      }
      __builtin_amdgcn_s_setprio(0);
    }
    __syncthreads();
    cur ^= 1;
  }

  // ---- epilogue: Y[b, q, h*64 + d] = O / l ----
#pragma unroll
  for (int qt = 0; qt < 2; ++qt) {
    float linv = 1.0f / ll[qt];
#pragma unroll
    for (int r = 0; r < 4; ++r) {
      float li = __shfl(linv, 4 * lg + r);
      int qg = qq0 + 16 * qt + 4 * lg + r;
      unsigned short* Yp = Y + ((size_t)(b * T_ + qg)) * D_ + h * 64;
#pragma unroll
      for (int t = 0; t < 4; ++t)
        Yp[16 * t + l15] = f2bf(o[qt][t][r] * li);
    }
  }
}

// ---------------- launch ----------------
extern "C" void kernel_launch(void* const* d_in, const int* in_sizes, int n_in,
                              void* d_out, int out_size, void* d_ws, size_t ws_size,
                              hipStream_t stream) {
  const float* x  = (const float*)d_in[0];
  const float* Wq = (const float*)d_in[1];
  const float* Wk = (const float*)d_in[2];
  const float* Wv = (const float*)d_in[3];
  const float* Wo = (const float*)d_in[4];
  float* out = (float*)d_out;

  const size_t NX = (size_t)M_ * D_;
  const size_t NW = (size_t)D_ * D_;
  const size_t need = (4 * NX + 4 * NW) * sizeof(unsigned short);
  if (ws_size < need) return;

  unsigned short* ws  = (unsigned short*)d_ws;
  unsigned short* xb  = ws;
  unsigned short* wqb = xb + NX;   // wqb/wkb/wvb contiguous = stacked QKV weight
  unsigned short* wkb = wqb + NW;
  unsigned short* wvb = wkb + NW;
  unsigned short* wob = wvb + NW;
  unsigned short* Qb  = wob + NW;  // Qb/Kb/Vtb contiguous = fused-QKV output
  unsigned short* Yb  = xb;        // alias: x dead after QKV projections

  cvt_all<<<12288, 256, 0, stream>>>(x, Wq, Wk, Wv, Wo, xb, wqb, wkb, wvb, wob);

  // fused QKV projection: C[8192, 3072] = x @ [Wq;Wk;Wv]^T
  gemm_bt<3><<<(M_ / 128) * (3072 / 128), 256, 0, stream>>>(xb, wqb, Qb, M_, 3072, D_);

  attn<<<B_ * H_ * (T_ / 128), 256, 0, stream>>>(Qb, Qb + NX, Qb + 2 * NX, Yb);

  gemm_bt<1><<<(M_ / 128) * (D_ / 128), 256, 0, stream>>>(Yb, wob, out, M_, D_, D_);
}

// Round 16
// 164.382 us; speedup vs baseline: 1.1252x; 1.0027x over previous
//
#include <hip/hip_runtime.h>

typedef __attribute__((ext_vector_type(8))) short short8;
typedef __attribute__((ext_vector_type(4))) float f32x4;
typedef __attribute__((ext_vector_type(2))) unsigned int u32x2;

constexpr int B_ = 4, T_ = 2048, D_ = 1024, H_ = 16;
constexpr int M_ = B_ * T_;          // 8192 token rows
constexpr float SCL2 = 0.1803368801111f;  // (1/sqrt(64)) * log2(e)

#if __has_builtin(__builtin_amdgcn_exp2f)
#define EXP2F __builtin_amdgcn_exp2f
#else
#define EXP2F exp2f
#endif

#define DEV __device__ __forceinline__

DEV unsigned short f2bf(float f) {   // f32 -> bf16 RNE
  unsigned int u = __builtin_bit_cast(unsigned int, f);
  u += 0x7FFFu + ((u >> 16) & 1u);
  return (unsigned short)(u >> 16);
}

DEV void gload16(const unsigned short* g, unsigned short* l) {
  __builtin_amdgcn_global_load_lds(
      (const __attribute__((address_space(1))) unsigned int*)g,
      (__attribute__((address_space(3))) unsigned int*)l, 16, 0, 0);
}

// ---------------- f32 -> bf16 conversion (x + 4 weights, one launch) -------
__global__ __launch_bounds__(256) void cvt_all(const float* __restrict__ x,
                                               const float* __restrict__ w0, const float* __restrict__ w1,
                                               const float* __restrict__ w2, const float* __restrict__ w3,
                                               unsigned short* __restrict__ xb,
                                               unsigned short* __restrict__ o0, unsigned short* __restrict__ o1,
                                               unsigned short* __restrict__ o2, unsigned short* __restrict__ o3) {
  int b = blockIdx.x;
  const float* in;
  unsigned short* out;
  int blk;
  if (b < 8192) { in = x; out = xb; blk = b; }
  else {
    int s = (b - 8192) >> 10;
    blk = (b - 8192) & 1023;
    in  = s == 0 ? w0 : s == 1 ? w1 : s == 2 ? w2 : w3;
    out = s == 0 ? o0 : s == 1 ? o1 : s == 2 ? o2 : o3;
  }
  int i = (blk * 256 + threadIdx.x) * 4;
  float4 f = *(const float4*)(in + i);
  ushort4 o;
  o.x = f2bf(f.x); o.y = f2bf(f.y); o.z = f2bf(f.z); o.w = f2bf(f.w);
  *(ushort4*)(out + i) = o;
}

// ---------------- GEMM: C[M,N] = A[M,K] * B[N,K]^T ----------------
// r13 structure (BK=64, T2 swizzle, 0 bank conflicts) + T4 issue-early
// counted-vmcnt loop:
//   barrier1 (WAR: all waves done reading buf[cur^1], iter t-1)
//   stage(t+1) -> buf[cur^1]
//   vmcnt(8)  (waits stage(t), issued a FULL iteration ago -> ~0 stall)
//   barrier2 (collectivizes per-wave vmcnt -> RAW safe)
//   compute(buf[cur])
// OUTMODE: 0 = bf16 row-major, 1 = f32 row-major,
//          3 = fused QKV: region by tn (0-7 Q, 8-15 K, 16-23 Vt-per-head)
template <int OUTMODE>
__global__ __launch_bounds__(256, 2) void gemm_bt(const unsigned short* __restrict__ A,
                                                  const unsigned short* __restrict__ B,
                                                  void* __restrict__ C,
                                                  int M, int N, int K) {
  constexpr int BM = 128, BN = 128, BK = 64;
  __shared__ __align__(16) unsigned short a_sh[2 * BM * BK];  // 32 KB
  __shared__ __align__(16) unsigned short b_sh[2 * BN * BK];  // 32 KB

  const int tid = threadIdx.x;
  const int lane = tid & 63;
  const int w = tid >> 6;
  const int l15 = lane & 15, lg = lane >> 4;
  const int wr = w >> 1, wc = w & 1;

  // XCD-chunked bijective swizzle: each XCD gets a contiguous run of tiles
  const int nwg = gridDim.x;
  const int swz = (blockIdx.x & 7) * (nwg >> 3) + (blockIdx.x >> 3);

  const int NT = N / BN;
  const int tm = swz / NT, tn = swz % NT;
  const unsigned short* Ab = A + (size_t)tm * BM * K;
  const unsigned short* Bb = B + (size_t)tn * BN * K;

  f32x4 acc[4][4];
#pragma unroll
  for (int m = 0; m < 4; ++m)
#pragma unroll
    for (int n = 0; n < 4; ++n) acc[m][n] = (f32x4){0.f, 0.f, 0.f, 0.f};

  // stage one BK=64 tile of A and B (8 gloads/thread), source-swizzled:
  // slot s of row r holds global k8-group (s ^ (r&7)).
  auto stage = [&](int buf, int kt) {
    int k0 = kt * BK;
#pragma unroll
    for (int rnd = 0; rnd < 4; ++rnd) {
      int c = rnd * 256 + tid;            // 16B chunk id, 0..1023
      int row = c >> 3, s = c & 7;        // 8 chunks per 64-elem row
      int koff = k0 + 8 * (s ^ (row & 7));
      unsigned short* ldst_a = a_sh + buf * BM * BK + (rnd * 256 + w * 64) * 8;
      unsigned short* ldst_b = b_sh + buf * BN * BK + (rnd * 256 + w * 64) * 8;
      gload16(Ab + (size_t)row * K + koff, ldst_a);
      gload16(Bb + (size_t)row * K + koff, ldst_b);
    }
  };

  stage(0, 0);
  int cur = 0;
  const int NK = K / BK;                  // 16
  for (int kt = 0; kt < NK; ++kt) {
    __builtin_amdgcn_s_barrier();         // WAR: buf[cur^1] reads (iter kt-1) done
    __builtin_amdgcn_sched_barrier(0);
    if (kt + 1 < NK) {
      stage(cur ^ 1, kt + 1);
      __builtin_amdgcn_sched_barrier(0);
      asm volatile("s_waitcnt vmcnt(8)" ::: "memory");  // stage(kt) landed; kt+1 in flight
    } else {
      asm volatile("s_waitcnt vmcnt(0)" ::: "memory");
    }
    __builtin_amdgcn_sched_barrier(0);
    __builtin_amdgcn_s_barrier();         // RAW: collectivize per-wave vmcnt
    __builtin_amdgcn_sched_barrier(0);

    const unsigned short* ab = a_sh + cur * BM * BK;
    const unsigned short* bb = b_sh + cur * BN * BK;
#pragma unroll
    for (int kk = 0; kk < 2; ++kk) {
      short8 af[4], bf8[4];
#pragma unroll
      for (int m = 0; m < 4; ++m) {
        int row = wr * 64 + m * 16 + l15;
        int slot = (kk * 4 + lg) ^ (row & 7);
        af[m] = *(const short8*)(ab + row * 64 + slot * 8);
      }
#pragma unroll
      for (int n = 0; n < 4; ++n) {
        int row = wc * 64 + n * 16 + l15;
        int slot = (kk * 4 + lg) ^ (row & 7);
        bf8[n] = *(const short8*)(bb + row * 64 + slot * 8);
      }
#pragma unroll
      for (int m = 0; m < 4; ++m)
#pragma unroll
        for (int n = 0; n < 4; ++n)
          acc[m][n] = __builtin_amdgcn_mfma_f32_16x16x32_bf16(af[m], bf8[n], acc[m][n], 0, 0, 0);
    }
    cur ^= 1;
  }

  const int row0 = tm * BM + wr * 64 + lg * 4;
  const int col0 = tn * BN + wc * 64 + l15;
#pragma unroll
  for (int m = 0; m < 4; ++m)
#pragma unroll
    for (int n = 0; n < 4; ++n) {
      if (OUTMODE == 3) {
        const int region = tn >> 3;               // 0=Q, 1=K, 2=V
        const int nc = col0 - (region << 10) + n * 16;
        const int mm = row0 + m * 16;
        if (region == 2) {
          // Vt-per-head: [(b*16+h)][d][s], r consecutive in s
          size_t base = (size_t)2 * 8388608 +
                        ((size_t)((mm >> 11) * 16 + (nc >> 6))) * 131072 +
                        (size_t)(nc & 63) * 2048 + (mm & 2047);
          ushort4 pk;
          pk.x = f2bf(acc[m][n][0]); pk.y = f2bf(acc[m][n][1]);
          pk.z = f2bf(acc[m][n][2]); pk.w = f2bf(acc[m][n][3]);
          *(ushort4*)((unsigned short*)C + base) = pk;
        } else {
          unsigned short* dst = (unsigned short*)C + (size_t)region * 8388608;
#pragma unroll
          for (int r = 0; r < 4; ++r)
            dst[(size_t)(mm + r) * 1024 + nc] = f2bf(acc[m][n][r]);
        }
      } else {
#pragma unroll
        for (int r = 0; r < 4; ++r) {
          size_t idx = (size_t)(row0 + m * 16 + r) * N + (col0 + n * 16);
          if (OUTMODE == 1)
            ((float*)C)[idx] = acc[m][n][r];
          else
            ((unsigned short*)C)[idx] = f2bf(acc[m][n][r]);
        }
      }
    }
}

// ---------------- causal flash attention (swapped-QK, KB=64, QB=128) --------
// r15 structure + same T4 issue-early counted-vmcnt loop (4 loads/thread ->
// vmcnt(4); prologue Q-frag loads are older than stage(0) so the count is
// conservative-correct). Barriers outside the active-branch (uniform).
__global__ __launch_bounds__(256, 3) void attn(const unsigned short* __restrict__ Q,
                                               const unsigned short* __restrict__ K,
                                               const unsigned short* __restrict__ Vt,
                                               unsigned short* __restrict__ Y) {
  __shared__ __align__(16) unsigned short k_sh[2][64 * 64];
  __shared__ __align__(16) unsigned short v_sh[2][64 * 64];   // [d][s], swizzled
  __shared__ __align__(16) unsigned short p_sh[4][32][72];    // per-wave P

  const int tid = threadIdx.x;
  const int lane = tid & 63;
  const int w = tid >> 6;
  const int l15 = lane & 15, lg = lane >> 4;

  const int bid = blockIdx.x;
  const int qt_blk = 15 - (bid >> 6);          // all heavy blocks dispatch first
  const int bh = (bid & 7) * 8 + ((bid >> 3) & 7);  // XCD-local KV reuse
  const int h = bh & 15;
  const int b = bh >> 4;
  const int q0 = qt_blk * 128;
  const int qq0 = q0 + 32 * w;                 // this wave's first q-row

  const unsigned short* Qp = Q + ((size_t)(b * T_ + q0)) * D_ + h * 64;
  const unsigned short* Kp = K + ((size_t)(b * T_)) * D_ + h * 64;
  const unsigned short* Vtp = Vt + (size_t)bh * 131072;   // [64 d][2048 s]

  auto stK = [&](int buf, int kv0) {
#pragma unroll
    for (int j = 0; j < 2; ++j) {
      int c = j * 256 + tid;
      int row = c >> 3;
      gload16(Kp + (size_t)(kv0 + row) * D_ + 8 * ((c & 7) ^ (row & 7)),
              &k_sh[buf][(j * 256 + w * 64) * 8]);
    }
  };
  auto stV = [&](int buf, int kv0) {
#pragma unroll
    for (int j = 0; j < 2; ++j) {
      int c = j * 256 + tid;
      int d = c >> 3;
      gload16(Vtp + (size_t)d * 2048 + kv0 + 8 * ((c & 7) ^ (d & 7)),
              &v_sh[buf][(j * 256 + w * 64) * 8]);
    }
  };

  // Q fragments direct global -> registers (B-frag: row = q, k-contig)
  short8 qf[2][2];
#pragma unroll
  for (int qt = 0; qt < 2; ++qt)
#pragma unroll
    for (int kk = 0; kk < 2; ++kk)
      qf[qt][kk] = *(const short8*)(Qp + (size_t)(32 * w + 16 * qt + l15) * D_ + 32 * kk + 8 * lg);

  stK(0, 0);
  stV(0, 0);

  unsigned short* p_w = &p_sh[w][0][0];

  const float NEGINF = -__builtin_inff();
  float ml[2] = {NEGINF, NEGINF};
  float ll[2] = {0.f, 0.f};
  f32x4 o[2][4];
#pragma unroll
  for (int qt = 0; qt < 2; ++qt)
#pragma unroll
    for (int t = 0; t < 4; ++t) o[qt][t] = (f32x4){0.f, 0.f, 0.f, 0.f};

  const int NI = 2 * qt_blk + 2;
  int cur = 0;
  for (int i = 0; i < NI; ++i) {
    const int kv0 = i * 64;
    __builtin_amdgcn_s_barrier();        // WAR: buf[cur^1] reads (iter i-1) done
    __builtin_amdgcn_sched_barrier(0);
    if (i + 1 < NI) {
      stK(cur ^ 1, kv0 + 64);
      stV(cur ^ 1, kv0 + 64);
      __builtin_amdgcn_sched_barrier(0);
      asm volatile("s_waitcnt vmcnt(4)" ::: "memory");  // stage(i) landed
    } else {
      asm volatile("s_waitcnt vmcnt(0)" ::: "memory");
    }
    __builtin_amdgcn_sched_barrier(0);
    __builtin_amdgcn_s_barrier();        // RAW: collectivize per-wave vmcnt
    __builtin_amdgcn_sched_barrier(0);

    const bool active = (kv0 <= qq0 + 31);
    if (active) {
      // ---- S^T = K * Q^T  (16 MFMA) ----
      f32x4 sacc[2][4];
#pragma unroll
      for (int qt = 0; qt < 2; ++qt)
#pragma unroll
        for (int t = 0; t < 4; ++t) sacc[qt][t] = (f32x4){0.f, 0.f, 0.f, 0.f};
      const char* kb = (const char*)k_sh[cur];
      __builtin_amdgcn_s_setprio(1);
#pragma unroll
      for (int t = 0; t < 4; ++t) {
        int sr = 16 * t + l15;
        int sw = (sr & 7) << 4;
        short8 kf0 = *(const short8*)(kb + sr * 128 + ((16 * lg) ^ sw));
        short8 kf1 = *(const short8*)(kb + sr * 128 + ((64 + 16 * lg) ^ sw));
#pragma unroll
        for (int qt = 0; qt < 2; ++qt) {
          sacc[qt][t] = __builtin_amdgcn_mfma_f32_16x16x32_bf16(kf0, qf[qt][0], sacc[qt][t], 0, 0, 0);
          sacc[qt][t] = __builtin_amdgcn_mfma_f32_16x16x32_bf16(kf1, qf[qt][1], sacc[qt][t], 0, 0, 0);
        }
      }
      __builtin_amdgcn_s_setprio(0);

      // ---- online softmax per q-tile (in-register, T13 defer-max) ----
      float corr[2];
      bool defer[2];
#pragma unroll
      for (int qt = 0; qt < 2; ++qt) {
        const bool nomask = (kv0 + 63) <= (qq0 + 16 * qt);   // wave-uniform
        float sv[16];
        if (nomask) {
#pragma unroll
          for (int t = 0; t < 4; ++t)
#pragma unroll
            for (int r = 0; r < 4; ++r) sv[4 * t + r] = sacc[qt][t][r];
        } else {
          const int qg = qq0 + 16 * qt + l15;
#pragma unroll
          for (int t = 0; t < 4; ++t)
#pragma unroll
            for (int r = 0; r < 4; ++r) {
              int sg = kv0 + 16 * t + 4 * lg + r;
              sv[4 * t + r] = (sg <= qg) ? sacc[qt][t][r] : NEGINF;
            }
        }
        float a8[8], a4[4], a2[2];
#pragma unroll
        for (int k = 0; k < 8; ++k) a8[k] = fmaxf(sv[k], sv[k + 8]);
#pragma unroll
        for (int k = 0; k < 4; ++k) a4[k] = fmaxf(a8[k], a8[k + 4]);
        a2[0] = fmaxf(a4[0], a4[2]); a2[1] = fmaxf(a4[1], a4[3]);
        float mx = fmaxf(a2[0], a2[1]);
        mx = fmaxf(mx, __shfl_xor(mx, 16));
        mx = fmaxf(mx, __shfl_xor(mx, 32));
        // T13: keep old max when growth small (P bounded by 2^(8*SCL2) ~ 2.7)
        defer[qt] = (__all(mx <= ml[qt] + 8.0f) != 0);
        float mnew = defer[qt] ? ml[qt] : fmaxf(ml[qt], mx);
        corr[qt] = defer[qt] ? 1.0f : EXP2F((ml[qt] - mnew) * SCL2);
        float nms2 = mnew * SCL2;
        float pv[16];
#pragma unroll
        for (int k = 0; k < 16; ++k) pv[k] = EXP2F(fmaf(sv[k], SCL2, -nms2));
        float s8[8], s4[4], s2[2];
#pragma unroll
        for (int k = 0; k < 8; ++k) s8[k] = pv[k] + pv[k + 8];
#pragma unroll
        for (int k = 0; k < 4; ++k) s4[k] = s8[k] + s8[k + 4];
        s2[0] = s4[0] + s4[2]; s2[1] = s4[1] + s4[3];
        float ps = s2[0] + s2[1];
        ps += __shfl_xor(ps, 16);
        ps += __shfl_xor(ps, 32);
        ll[qt] = ll[qt] * corr[qt] + ps;
        ml[qt] = mnew;
        // pack P -> LDS via v_cvt_pk_bf16_f32 (RNE, lo=src0)
#pragma unroll
        for (int t = 0; t < 4; ++t) {
          unsigned lo, hi;
          asm("v_cvt_pk_bf16_f32 %0, %1, %2" : "=v"(lo) : "v"(pv[4 * t]), "v"(pv[4 * t + 1]));
          asm("v_cvt_pk_bf16_f32 %0, %1, %2" : "=v"(hi) : "v"(pv[4 * t + 2]), "v"(pv[4 * t + 3]));
          u32x2 pk = {lo, hi};
          *(u32x2*)(void*)(p_w + (16 * qt + l15) * 72 + 16 * t + 4 * lg) = pk;
        }
      }
      asm volatile("" ::: "memory");  // order P stores before P frag loads

      // ---- rescale O (skipped when deferred) ----
#pragma unroll
      for (int qt = 0; qt < 2; ++qt)
        if (!defer[qt]) {
#pragma unroll
          for (int r = 0; r < 4; ++r) {
            float cr = __shfl(corr[qt], 4 * lg + r);
#pragma unroll
            for (int t = 0; t < 4; ++t) o[qt][t][r] *= cr;
          }
        }

      // ---- O += P * V  (16 MFMA) ----
      short8 pa[2][2];
#pragma unroll
      for (int qt = 0; qt < 2; ++qt)
#pragma unroll
        for (int kk = 0; kk < 2; ++kk)
          pa[qt][kk] = *(const short8*)(p_w + (16 * qt + l15) * 72 + kk * 32 + 8 * lg);

      const char* vbT = (const char*)v_sh[cur];
      __builtin_amdgcn_s_setprio(1);
#pragma unroll
      for (int t = 0; t < 4; ++t) {
        int dr = 16 * t + l15;
        int sw = (dr & 7) << 4;
        short8 vf0 = *(const short8*)(vbT + dr * 128 + ((16 * lg) ^ sw));
        short8 vf1 = *(const short8*)(vbT + dr * 128 + ((64 + 16 * lg) ^ sw));
#pragma unroll
        for (int qt = 0; qt < 2; ++qt) {
          o[qt][t] = __builtin_amdgcn_mfma_f32_16x16x32_bf16(pa[qt][0], vf0, o[qt][t], 0, 0, 0);
          o[qt][t] = __builtin_amdgcn_mfma_f32_16x16x32_bf16(pa[qt][1], vf1, o[qt][t], 0, 0, 0);
        }
      }
      __builtin_amdgcn_s_setprio(0);
    }
    cur ^= 1;
  }

  // ---- epilogue: Y[b, q, h*64 + d] = O / l ----
#pragma unroll
  for (int qt = 0; qt < 2; ++qt) {
    float linv = 1.0f / ll[qt];
#pragma unroll
    for (int r = 0; r < 4; ++r) {
      float li = __shfl(linv, 4 * lg + r);
      int qg = qq0 + 16 * qt + 4 * lg + r;
      unsigned short* Yp = Y + ((size_t)(b * T_ + qg)) * D_ + h * 64;
#pragma unroll
      for (int t = 0; t < 4; ++t)
        Yp[16 * t + l15] = f2bf(o[qt][t][r] * li);
    }
  }
}

// ---------------- launch ----------------
extern "C" void kernel_launch(void* const* d_in, const int* in_sizes, int n_in,
                              void* d_out, int out_size, void* d_ws, size_t ws_size,
                              hipStream_t stream) {
  const float* x  = (const float*)d_in[0];
  const float* Wq = (const float*)d_in[1];
  const float* Wk = (const float*)d_in[2];
  const float* Wv = (const float*)d_in[3];
  const float* Wo = (const float*)d_in[4];
  float* out = (float*)d_out;

  const size_t NX = (size_t)M_ * D_;
  const size_t NW = (size_t)D_ * D_;
  const size_t need = (4 * NX + 4 * NW) * sizeof(unsigned short);
  if (ws_size < need) return;

  unsigned short* ws  = (unsigned short*)d_ws;
  unsigned short* xb  = ws;
  unsigned short* wqb = xb + NX;   // wqb/wkb/wvb contiguous = stacked QKV weight
  unsigned short* wkb = wqb + NW;
  unsigned short* wvb = wkb + NW;
  unsigned short* wob = wvb + NW;
  unsigned short* Qb  = wob + NW;  // Qb/Kb/Vtb contiguous = fused-QKV output
  unsigned short* Yb  = xb;        // alias: x dead after QKV projections

  cvt_all<<<12288, 256, 0, stream>>>(x, Wq, Wk, Wv, Wo, xb, wqb, wkb, wvb, wob);

  // fused QKV projection: C[8192, 3072] = x @ [Wq;Wk;Wv]^T
  gemm_bt<3><<<(M_ / 128) * (3072 / 128), 256, 0, stream>>>(xb, wqb, Qb, M_, 3072, D_);

  attn<<<B_ * H_ * (T_ / 128), 256, 0, stream>>>(Qb, Qb + NX, Qb + 2 * NX, Yb);

  gemm_bt<1><<<(M_ / 128) * (D_ / 128), 256, 0, stream>>>(Yb, wob, out, M_, D_, D_);
}

// Round 17
// 158.342 us; speedup vs baseline: 1.1681x; 1.0381x over previous
//
#include <hip/hip_runtime.h>

typedef __attribute__((ext_vector_type(8))) short short8;
typedef __attribute__((ext_vector_type(4))) float f32x4;
typedef __attribute__((ext_vector_type(2))) unsigned int u32x2;

constexpr int B_ = 4, T_ = 2048, D_ = 1024, H_ = 16;
constexpr int M_ = B_ * T_;          // 8192 token rows
constexpr float SCL2 = 0.1803368801111f;  // (1/sqrt(64)) * log2(e)

#if __has_builtin(__builtin_amdgcn_exp2f)
#define EXP2F __builtin_amdgcn_exp2f
#else
#define EXP2F exp2f
#endif

#define DEV __device__ __forceinline__

DEV unsigned short f2bf(float f) {   // f32 -> bf16 RNE
  unsigned int u = __builtin_bit_cast(unsigned int, f);
  u += 0x7FFFu + ((u >> 16) & 1u);
  return (unsigned short)(u >> 16);
}

DEV void gload16(const unsigned short* g, unsigned short* l) {
  __builtin_amdgcn_global_load_lds(
      (const __attribute__((address_space(1))) unsigned int*)g,
      (__attribute__((address_space(3))) unsigned int*)l, 16, 0, 0);
}

// ---------------- f32 -> bf16 conversion (x + 4 weights, one launch) -------
__global__ __launch_bounds__(256) void cvt_all(const float* __restrict__ x,
                                               const float* __restrict__ w0, const float* __restrict__ w1,
                                               const float* __restrict__ w2, const float* __restrict__ w3,
                                               unsigned short* __restrict__ xb,
                                               unsigned short* __restrict__ o0, unsigned short* __restrict__ o1,
                                               unsigned short* __restrict__ o2, unsigned short* __restrict__ o3) {
  int b = blockIdx.x;
  const float* in;
  unsigned short* out;
  int blk;
  if (b < 8192) { in = x; out = xb; blk = b; }
  else {
    int s = (b - 8192) >> 10;
    blk = (b - 8192) & 1023;
    in  = s == 0 ? w0 : s == 1 ? w1 : s == 2 ? w2 : w3;
    out = s == 0 ? o0 : s == 1 ? o1 : s == 2 ? o2 : o3;
  }
  int i = (blk * 256 + threadIdx.x) * 4;
  float4 f = *(const float4*)(in + i);
  ushort4 o;
  o.x = f2bf(f.x); o.y = f2bf(f.y); o.z = f2bf(f.z); o.w = f2bf(f.w);
  *(ushort4*)(out + i) = o;
}

// ---------------- GEMM: C[M,N] = A[M,K] * B[N,K]^T ----------------
// r13 structure (BK=64, T2 swizzle, 0 bank conflicts) + T4 issue-early
// counted-vmcnt loop, K-loop unrolled x2 so ALL buffer indices are
// compile-time static (no cur-dependent address VALU per iteration).
// OUTMODE: 0 = bf16 row-major, 1 = f32 row-major,
//          3 = fused QKV: region by tn (0-7 Q, 8-15 K, 16-23 Vt-per-head)
template <int OUTMODE>
__global__ __launch_bounds__(256, 2) void gemm_bt(const unsigned short* __restrict__ A,
                                                  const unsigned short* __restrict__ B,
                                                  void* __restrict__ C,
                                                  int M, int N, int K) {
  constexpr int BM = 128, BN = 128, BK = 64;
  __shared__ __align__(16) unsigned short a_sh[2 * BM * BK];  // 32 KB
  __shared__ __align__(16) unsigned short b_sh[2 * BN * BK];  // 32 KB

  const int tid = threadIdx.x;
  const int lane = tid & 63;
  const int w = tid >> 6;
  const int l15 = lane & 15, lg = lane >> 4;
  const int wr = w >> 1, wc = w & 1;

  // XCD-chunked bijective swizzle: each XCD gets a contiguous run of tiles
  const int nwg = gridDim.x;
  const int swz = (blockIdx.x & 7) * (nwg >> 3) + (blockIdx.x >> 3);

  const int NT = N / BN;
  const int tm = swz / NT, tn = swz % NT;
  const unsigned short* Ab = A + (size_t)tm * BM * K;
  const unsigned short* Bb = B + (size_t)tn * BN * K;

  f32x4 acc[4][4];
#pragma unroll
  for (int m = 0; m < 4; ++m)
#pragma unroll
    for (int n = 0; n < 4; ++n) acc[m][n] = (f32x4){0.f, 0.f, 0.f, 0.f};

  // stage one BK=64 tile of A and B (8 gloads/thread), source-swizzled:
  // slot s of row r holds global k8-group (s ^ (r&7)). buf is a constant.
  auto stage = [&](int buf, int kt) {
    int k0 = kt * BK;
#pragma unroll
    for (int rnd = 0; rnd < 4; ++rnd) {
      int c = rnd * 256 + tid;            // 16B chunk id, 0..1023
      int row = c >> 3, s = c & 7;        // 8 chunks per 64-elem row
      int koff = k0 + 8 * (s ^ (row & 7));
      unsigned short* ldst_a = a_sh + buf * BM * BK + (rnd * 256 + w * 64) * 8;
      unsigned short* ldst_b = b_sh + buf * BN * BK + (rnd * 256 + w * 64) * 8;
      gload16(Ab + (size_t)row * K + koff, ldst_a);
      gload16(Bb + (size_t)row * K + koff, ldst_b);
    }
  };

  // compute one K-tile from static buffer pointers
  auto compute = [&](const unsigned short* ab, const unsigned short* bb) {
#pragma unroll
    for (int kk = 0; kk < 2; ++kk) {
      short8 af[4], bf8[4];
#pragma unroll
      for (int m = 0; m < 4; ++m) {
        int row = wr * 64 + m * 16 + l15;
        int slot = (kk * 4 + lg) ^ (row & 7);
        af[m] = *(const short8*)(ab + row * 64 + slot * 8);
      }
#pragma unroll
      for (int n = 0; n < 4; ++n) {
        int row = wc * 64 + n * 16 + l15;
        int slot = (kk * 4 + lg) ^ (row & 7);
        bf8[n] = *(const short8*)(bb + row * 64 + slot * 8);
      }
#pragma unroll
      for (int m = 0; m < 4; ++m)
#pragma unroll
        for (int n = 0; n < 4; ++n)
          acc[m][n] = __builtin_amdgcn_mfma_f32_16x16x32_bf16(af[m], bf8[n], acc[m][n], 0, 0, 0);
    }
  };

  const int NK = K / BK;                  // 16 (even)
  stage(0, 0);
  for (int kt = 0; kt < NK; kt += 2) {
    // ---- sub-iteration A: compute buf0 (K-tile kt), stage buf1 (kt+1) ----
    __builtin_amdgcn_s_barrier();         // WAR: buf1 reads (iter kt-1) done
    __builtin_amdgcn_sched_barrier(0);
    {                                     // kt+1 < NK always (kt <= NK-2)
      stage(1, kt + 1);
      __builtin_amdgcn_sched_barrier(0);
      asm volatile("s_waitcnt vmcnt(8)" ::: "memory");  // stage(kt) landed
    }
    __builtin_amdgcn_sched_barrier(0);
    __builtin_amdgcn_s_barrier();         // RAW: collectivize per-wave vmcnt
    __builtin_amdgcn_sched_barrier(0);
    compute(a_sh, b_sh);

    // ---- sub-iteration B: compute buf1 (K-tile kt+1), stage buf0 (kt+2) ----
    __builtin_amdgcn_s_barrier();
    __builtin_amdgcn_sched_barrier(0);
    if (kt + 2 < NK) {
      stage(0, kt + 2);
      __builtin_amdgcn_sched_barrier(0);
      asm volatile("s_waitcnt vmcnt(8)" ::: "memory");
    } else {
      asm volatile("s_waitcnt vmcnt(0)" ::: "memory");
    }
    __builtin_amdgcn_sched_barrier(0);
    __builtin_amdgcn_s_barrier();
    __builtin_amdgcn_sched_barrier(0);
    compute(a_sh + BM * BK, b_sh + BN * BK);
  }

  const int row0 = tm * BM + wr * 64 + lg * 4;
  const int col0 = tn * BN + wc * 64 + l15;
#pragma unroll
  for (int m = 0; m < 4; ++m)
#pragma unroll
    for (int n = 0; n < 4; ++n) {
      if (OUTMODE == 3) {
        const int region = tn >> 3;               // 0=Q, 1=K, 2=V
        const int nc = col0 - (region << 10) + n * 16;
        const int mm = row0 + m * 16;
        if (region == 2) {
          // Vt-per-head: [(b*16+h)][d][s], r consecutive in s
          size_t base = (size_t)2 * 8388608 +
                        ((size_t)((mm >> 11) * 16 + (nc >> 6))) * 131072 +
                        (size_t)(nc & 63) * 2048 + (mm & 2047);
          ushort4 pk;
          pk.x = f2bf(acc[m][n][0]); pk.y = f2bf(acc[m][n][1]);
          pk.z = f2bf(acc[m][n][2]); pk.w = f2bf(acc[m][n][3]);
          *(ushort4*)((unsigned short*)C + base) = pk;
        } else {
          unsigned short* dst = (unsigned short*)C + (size_t)region * 8388608;
#pragma unroll
          for (int r = 0; r < 4; ++r)
            dst[(size_t)(mm + r) * 1024 + nc] = f2bf(acc[m][n][r]);
        }
      } else {
#pragma unroll
        for (int r = 0; r < 4; ++r) {
          size_t idx = (size_t)(row0 + m * 16 + r) * N + (col0 + n * 16);
          if (OUTMODE == 1)
            ((float*)C)[idx] = acc[m][n][r];
          else
            ((unsigned short*)C)[idx] = f2bf(acc[m][n][r]);
        }
      }
    }
}

// ---------------- causal flash attention (swapped-QK, KB=64, QB=128) --------
// r16 structure, KV-loop unrolled x2 (NI even) for static buffer indices.
__global__ __launch_bounds__(256, 3) void attn(const unsigned short* __restrict__ Q,
                                               const unsigned short* __restrict__ K,
                                               const unsigned short* __restrict__ Vt,
                                               unsigned short* __restrict__ Y) {
  __shared__ __align__(16) unsigned short k_sh[2][64 * 64];
  __shared__ __align__(16) unsigned short v_sh[2][64 * 64];   // [d][s], swizzled
  __shared__ __align__(16) unsigned short p_sh[4][32][72];    // per-wave P

  const int tid = threadIdx.x;
  const int lane = tid & 63;
  const int w = tid >> 6;
  const int l15 = lane & 15, lg = lane >> 4;

  const int bid = blockIdx.x;
  const int qt_blk = 15 - (bid >> 6);          // all heavy blocks dispatch first
  const int bh = (bid & 7) * 8 + ((bid >> 3) & 7);  // XCD-local KV reuse
  const int h = bh & 15;
  const int b = bh >> 4;
  const int q0 = qt_blk * 128;
  const int qq0 = q0 + 32 * w;                 // this wave's first q-row

  const unsigned short* Qp = Q + ((size_t)(b * T_ + q0)) * D_ + h * 64;
  const unsigned short* Kp = K + ((size_t)(b * T_)) * D_ + h * 64;
  const unsigned short* Vtp = Vt + (size_t)bh * 131072;   // [64 d][2048 s]

  auto stK = [&](int buf, int kv0) {
#pragma unroll
    for (int j = 0; j < 2; ++j) {
      int c = j * 256 + tid;
      int row = c >> 3;
      gload16(Kp + (size_t)(kv0 + row) * D_ + 8 * ((c & 7) ^ (row & 7)),
              &k_sh[buf][(j * 256 + w * 64) * 8]);
    }
  };
  auto stV = [&](int buf, int kv0) {
#pragma unroll
    for (int j = 0; j < 2; ++j) {
      int c = j * 256 + tid;
      int d = c >> 3;
      gload16(Vtp + (size_t)d * 2048 + kv0 + 8 * ((c & 7) ^ (d & 7)),
              &v_sh[buf][(j * 256 + w * 64) * 8]);
    }
  };

  // Q fragments direct global -> registers (B-frag: row = q, k-contig)
  short8 qf[2][2];
#pragma unroll
  for (int qt = 0; qt < 2; ++qt)
#pragma unroll
    for (int kk = 0; kk < 2; ++kk)
      qf[qt][kk] = *(const short8*)(Qp + (size_t)(32 * w + 16 * qt + l15) * D_ + 32 * kk + 8 * lg);

  stK(0, 0);
  stV(0, 0);

  unsigned short* p_w = &p_sh[w][0][0];

  const float NEGINF = -__builtin_inff();
  float ml[2] = {NEGINF, NEGINF};
  float ll[2] = {0.f, 0.f};
  f32x4 o[2][4];
#pragma unroll
  for (int qt = 0; qt < 2; ++qt)
#pragma unroll
    for (int t = 0; t < 4; ++t) o[qt][t] = (f32x4){0.f, 0.f, 0.f, 0.f};

  // one KV-tile body (static buffer pointers)
  auto body = [&](const unsigned short* kbuf, const unsigned short* vbuf, int kv0) {
    // ---- S^T = K * Q^T  (16 MFMA) ----
    f32x4 sacc[2][4];
#pragma unroll
    for (int qt = 0; qt < 2; ++qt)
#pragma unroll
      for (int t = 0; t < 4; ++t) sacc[qt][t] = (f32x4){0.f, 0.f, 0.f, 0.f};
    const char* kb = (const char*)kbuf;
    __builtin_amdgcn_s_setprio(1);
#pragma unroll
    for (int t = 0; t < 4; ++t) {
      int sr = 16 * t + l15;
      int sw = (sr & 7) << 4;
      short8 kf0 = *(const short8*)(kb + sr * 128 + ((16 * lg) ^ sw));
      short8 kf1 = *(const short8*)(kb + sr * 128 + ((64 + 16 * lg) ^ sw));
#pragma unroll
      for (int qt = 0; qt < 2; ++qt) {
        sacc[qt][t] = __builtin_amdgcn_mfma_f32_16x16x32_bf16(kf0, qf[qt][0], sacc[qt][t], 0, 0, 0);
        sacc[qt][t] = __builtin_amdgcn_mfma_f32_16x16x32_bf16(kf1, qf[qt][1], sacc[qt][t], 0, 0, 0);
      }
    }
    __builtin_amdgcn_s_setprio(0);

    // ---- online softmax per q-tile (in-register, T13 defer-max) ----
    float corr[2];
    bool defer[2];
#pragma unroll
    for (int qt = 0; qt < 2; ++qt) {
      const bool nomask = (kv0 + 63) <= (qq0 + 16 * qt);   // wave-uniform
      float sv[16];
      if (nomask) {
#pragma unroll
        for (int t = 0; t < 4; ++t)
#pragma unroll
          for (int r = 0; r < 4; ++r) sv[4 * t + r] = sacc[qt][t][r];
      } else {
        const int qg = qq0 + 16 * qt + l15;
#pragma unroll
        for (int t = 0; t < 4; ++t)
#pragma unroll
          for (int r = 0; r < 4; ++r) {
            int sg = kv0 + 16 * t + 4 * lg + r;
            sv[4 * t + r] = (sg <= qg) ? sacc[qt][t][r] : NEGINF;
          }
      }
      float a8[8], a4[4], a2[2];
#pragma unroll
      for (int k = 0; k < 8; ++k) a8[k] = fmaxf(sv[k], sv[k + 8]);
#pragma unroll
      for (int k = 0; k < 4; ++k) a4[k] = fmaxf(a8[k], a8[k + 4]);
      a2[0] = fmaxf(a4[0], a4[2]); a2[1] = fmaxf(a4[1], a4[3]);
      float mx = fmaxf(a2[0], a2[1]);
      mx = fmaxf(mx, __shfl_xor(mx, 16));
      mx = fmaxf(mx, __shfl_xor(mx, 32));
      // T13: keep old max when growth small (P bounded by 2^(8*SCL2) ~ 2.7)
      defer[qt] = (__all(mx <= ml[qt] + 8.0f) != 0);
      float mnew = defer[qt] ? ml[qt] : fmaxf(ml[qt], mx);
      corr[qt] = defer[qt] ? 1.0f : EXP2F((ml[qt] - mnew) * SCL2);
      float nms2 = mnew * SCL2;
      float pv[16];
#pragma unroll
      for (int k = 0; k < 16; ++k) pv[k] = EXP2F(fmaf(sv[k], SCL2, -nms2));
      float s8[8], s4[4], s2[2];
#pragma unroll
      for (int k = 0; k < 8; ++k) s8[k] = pv[k] + pv[k + 8];
#pragma unroll
      for (int k = 0; k < 4; ++k) s4[k] = s8[k] + s8[k + 4];
      s2[0] = s4[0] + s4[2]; s2[1] = s4[1] + s4[3];
      float ps = s2[0] + s2[1];
      ps += __shfl_xor(ps, 16);
      ps += __shfl_xor(ps, 32);
      ll[qt] = ll[qt] * corr[qt] + ps;
      ml[qt] = mnew;
      // pack P -> LDS via v_cvt_pk_bf16_f32 (RNE, lo=src0)
#pragma unroll
      for (int t = 0; t < 4; ++t) {
        unsigned lo, hi;
        asm("v_cvt_pk_bf16_f32 %0, %1, %2" : "=v"(lo) : "v"(pv[4 * t]), "v"(pv[4 * t + 1]));
        asm("v_cvt_pk_bf16_f32 %0, %1, %2" : "=v"(hi) : "v"(pv[4 * t + 2]), "v"(pv[4 * t + 3]));
        u32x2 pk = {lo, hi};
        *(u32x2*)(void*)(p_w + (16 * qt + l15) * 72 + 16 * t + 4 * lg) = pk;
      }
    }
    asm volatile("" ::: "memory");  // order P stores before P frag loads

    // ---- rescale O (skipped when deferred) ----
#pragma unroll
    for (int qt = 0; qt < 2; ++qt)
      if (!defer[qt]) {
#pragma unroll
        for (int r = 0; r < 4; ++r) {
          float cr = __shfl(corr[qt], 4 * lg + r);
#pragma unroll
          for (int t = 0; t < 4; ++t) o[qt][t][r] *= cr;
        }
      }

    // ---- O += P * V  (16 MFMA) ----
    short8 pa[2][2];
#pragma unroll
    for (int qt = 0; qt < 2; ++qt)
#pragma unroll
      for (int kk = 0; kk < 2; ++kk)
        pa[qt][kk] = *(const short8*)(p_w + (16 * qt + l15) * 72 + kk * 32 + 8 * lg);

    const char* vbT = (const char*)vbuf;
    __builtin_amdgcn_s_setprio(1);
#pragma unroll
    for (int t = 0; t < 4; ++t) {
      int dr = 16 * t + l15;
      int sw = (dr & 7) << 4;
      short8 vf0 = *(const short8*)(vbT + dr * 128 + ((16 * lg) ^ sw));
      short8 vf1 = *(const short8*)(vbT + dr * 128 + ((64 + 16 * lg) ^ sw));
#pragma unroll
      for (int qt = 0; qt < 2; ++qt) {
        o[qt][t] = __builtin_amdgcn_mfma_f32_16x16x32_bf16(pa[qt][0], vf0, o[qt][t], 0, 0, 0);
        o[qt][t] = __builtin_amdgcn_mfma_f32_16x16x32_bf16(pa[qt][1], vf1, o[qt][t], 0, 0, 0);
      }
    }
    __builtin_amdgcn_s_setprio(0);
  };

  const int NI = 2 * qt_blk + 2;   // even
  for (int i = 0; i < NI; i += 2) {
    const int kv0 = i * 64;
    // ---- sub A: compute buf0 (tile i), stage buf1 (tile i+1) ----
    __builtin_amdgcn_s_barrier();        // WAR: buf1 reads (iter i-1) done
    __builtin_amdgcn_sched_barrier(0);
    {                                    // i+1 < NI always (i <= NI-2)
      stK(1, kv0 + 64);
      stV(1, kv0 + 64);
      __builtin_amdgcn_sched_barrier(0);
      asm volatile("s_waitcnt vmcnt(4)" ::: "memory");  // stage(i) landed
    }
    __builtin_amdgcn_sched_barrier(0);
    __builtin_amdgcn_s_barrier();        // RAW: collectivize per-wave vmcnt
    __builtin_amdgcn_sched_barrier(0);
    if (kv0 <= qq0 + 31) body(k_sh[0], v_sh[0], kv0);

    // ---- sub B: compute buf1 (tile i+1), stage buf0 (tile i+2) ----
    const int kv0b = kv0 + 64;
    __builtin_amdgcn_s_barrier();
    __builtin_amdgcn_sched_barrier(0);
    if (i + 2 < NI) {
      stK(0, kv0b + 64);
      stV(0, kv0b + 64);
      __builtin_amdgcn_sched_barrier(0);
      asm volatile("s_waitcnt vmcnt(4)" ::: "memory");
    } else {
      asm volatile("s_waitcnt vmcnt(0)" ::: "memory");
    }
    __builtin_amdgcn_sched_barrier(0);
    __builtin_amdgcn_s_barrier();
    __builtin_amdgcn_sched_barrier(0);
    if (kv0b <= qq0 + 31) body(k_sh[1], v_sh[1], kv0b);
  }

  // ---- epilogue: Y[b, q, h*64 + d] = O / l ----
#pragma unroll
  for (int qt = 0; qt < 2; ++qt) {
    float linv = 1.0f / ll[qt];
#pragma unroll
    for (int r = 0; r < 4; ++r) {
      float li = __shfl(linv, 4 * lg + r);
      int qg = qq0 + 16 * qt + 4 * lg + r;
      unsigned short* Yp = Y + ((size_t)(b * T_ + qg)) * D_ + h * 64;
#pragma unroll
      for (int t = 0; t < 4; ++t)
        Yp[16 * t + l15] = f2bf(o[qt][t][r] * li);
    }
  }
}

// ---------------- launch ----------------
extern "C" void kernel_launch(void* const* d_in, const int* in_sizes, int n_in,
                              void* d_out, int out_size, void* d_ws, size_t ws_size,
                              hipStream_t stream) {
  const float* x  = (const float*)d_in[0];
  const float* Wq = (const float*)d_in[1];
  const float* Wk = (const float*)d_in[2];
  const float* Wv = (const float*)d_in[3];
  const float* Wo = (const float*)d_in[4];
  float* out = (float*)d_out;

  const size_t NX = (size_t)M_ * D_;
  const size_t NW = (size_t)D_ * D_;
  const size_t need = (4 * NX + 4 * NW) * sizeof(unsigned short);
  if (ws_size < need) return;

  unsigned short* ws  = (unsigned short*)d_ws;
  unsigned short* xb  = ws;
  unsigned short* wqb = xb + NX;   // wqb/wkb/wvb contiguous = stacked QKV weight
  unsigned short* wkb = wqb + NW;
  unsigned short* wvb = wkb + NW;
  unsigned short* wob = wvb + NW;
  unsigned short* Qb  = wob + NW;  // Qb/Kb/Vtb contiguous = fused-QKV output
  unsigned short* Yb  = xb;        // alias: x dead after QKV projections

  cvt_all<<<12288, 256, 0, stream>>>(x, Wq, Wk, Wv, Wo, xb, wqb, wkb, wvb, wob);

  // fused QKV projection: C[8192, 3072] = x @ [Wq;Wk;Wv]^T
  gemm_bt<3><<<(M_ / 128) * (3072 / 128), 256, 0, stream>>>(xb, wqb, Qb, M_, 3072, D_);

  attn<<<B_ * H_ * (T_ / 128), 256, 0, stream>>>(Qb, Qb + NX, Qb + 2 * NX, Yb);

  gemm_bt<1><<<(M_ / 128) * (D_ / 128), 256, 0, stream>>>(Yb, wob, out, M_, D_, D_);
}